// Round 6
// baseline (320.007 us; speedup 1.0000x reference)
//
#include <hip/hip_runtime.h>
#include <hip/hip_bf16.h>

using bf16x8 = __bf16 __attribute__((ext_vector_type(8)));
using f32x4  = float  __attribute__((ext_vector_type(4)));
using u16x8  = unsigned short __attribute__((ext_vector_type(8)));
using u16x4  = unsigned short __attribute__((ext_vector_type(4)));

__device__ __forceinline__ unsigned short f2bf(float f) {
  unsigned u = __builtin_bit_cast(unsigned, f);
  u += 0x7fffu + ((u >> 16) & 1u);
  return (unsigned short)(u >> 16);
}
__device__ __forceinline__ float bf2f(unsigned short h) {
  return __builtin_bit_cast(float, (unsigned)h << 16);
}

__device__ __forceinline__ void gload16(const void* g, void* l) {
  __builtin_amdgcn_global_load_lds(
      (const __attribute__((address_space(1))) void*)g,
      (__attribute__((address_space(3))) void*)l, 16, 0, 0);
}

__device__ __forceinline__ void barrier_raw() {
  asm volatile("" ::: "memory");
  __builtin_amdgcn_s_barrier();
  asm volatile("" ::: "memory");
}
#define VMC4() asm volatile("s_waitcnt vmcnt(4)" ::: "memory")
#define VMC0() asm volatile("s_waitcnt vmcnt(0)" ::: "memory")

// ---------------- convert f32 -> bf16 (vectorized) ----------------
__global__ __launch_bounds__(256) void conv_f32_bf16(const float* __restrict__ in,
                                                     unsigned short* __restrict__ out, int n) {
  int stride = gridDim.x * 256 * 4;
  for (int i = (blockIdx.x * 256 + threadIdx.x) * 4; i < n; i += stride) {
    float4 v = *reinterpret_cast<const float4*>(in + i);
    u16x4 o = { f2bf(v.x), f2bf(v.y), f2bf(v.z), f2bf(v.w) };
    *reinterpret_cast<u16x4*>(out + i) = o;
  }
}

// ---------------- transpose + convert: out[c][r] = bf16(in[r][c]) ----------------
__global__ __launch_bounds__(256) void transpose_f32_bf16(const float* __restrict__ in,
                                                          unsigned short* __restrict__ out,
                                                          int R, int C) {
  __shared__ float t[64][65];
  int c0 = blockIdx.x * 64, r0 = blockIdx.y * 64;
  int lx = threadIdx.x & 63, ly = threadIdx.x >> 6;
#pragma unroll
  for (int i = 0; i < 16; ++i) {
    int r = ly * 16 + i;
    t[r][lx] = in[(size_t)(r0 + r) * C + c0 + lx];
  }
  __syncthreads();
#pragma unroll
  for (int i = 0; i < 16; ++i) {
    int c = ly * 16 + i;
    out[(size_t)(c0 + c) * R + r0 + lx] = f2bf(t[lx][c]);
  }
}

// ============ 256x256, BK=64, 8-wave, software-pipelined GEMM mainloop ============
// LDS per buffer (64KB): A halves at +0/+16384, B halves at +32768/+49152.
// Double buffer (128KB). Reads XOR-swizzled (byte ^= (row&7)<<4); stages use
// linear LDS dest + inverse-swizzled global source (involution).
// Pipelined schedule per K-step (quadrants Q1=m0-3xn0-1, Q2=m0-3xn2-3,
// Q3=m4-7xn2-3, Q4=m4-7xn0-1), reads issued ONE phase before consumption,
// only 2 barriers per K-step:
//   P1: stage A(t+1)->nxt; read bH(n2-3,cur); MFMA Q1
//   P2: read aR(m4-7,cur); MFMA Q2
//   P3: MFMA Q3; BARRIER (B(t) reads done before B(t+2) stage)
//   P4: stage B(t+2)->cur; vmcnt(4); BARRIER (tile t+1 landed, all waves);
//       read aQ(m0-3,nxt)+bL(n0-1,nxt); MFMA Q4
// vmcnt: steady state 12 in flight at the wait; vmcnt(4) drains exactly
// tile t+1 (B staged prev P4, A staged this P1), leaving B(t+2) in flight.
__device__ __forceinline__ void gemm256_mainloop(
    const unsigned short* __restrict__ A, const unsigned short* __restrict__ Bt,
    int brow, int bcol, char* lds, f32x4 (&acc)[8][4]) {
  constexpr int NT = 16;  // K = 1024 / 64
  const int tid  = threadIdx.x;
  const int lane = tid & 63;
  const int w    = tid >> 6;
  const int wr   = w >> 2, wc = w & 3;
  const int lr   = lane & 15, kg = lane >> 4;

  const int o0 = tid * 16;
  const int o1 = 8192 + tid * 16;
  const int p0 = o0 ^ (((o0 >> 7) & 7) << 4);
  const int p1 = o1 ^ (((o1 >> 7) & 7) << 4);
  const int off0 = (p0 >> 7) * 2048 + (p0 & 127);
  const int off1 = (p1 >> 7) * 2048 + (p1 & 127);
  const int wq = w << 10;

  const int xr  = (lr & 7) << 4;
  const int ck0 = (kg * 16) ^ xr;
  const int ck1 = (64 + kg * 16) ^ xr;
  const int aoff = wr * 16384 + lr * 128;
  const int boff = 32768 + (wc >> 1) * 16384 + (wc & 1) * 8192 + lr * 128;

  auto STAGE = [&](const unsigned short* G, int rowbase, int t, int region) {
    const char* gb = (const char*)(G + (size_t)rowbase * 1024 + t * 64);
    char* lb = lds + region + wq;
    gload16(gb + off0, lb);
    gload16(gb + off1, lb + 8192);
  };

  bf16x8 aQ[4][2], aR[4][2], bL0[2][2], bL1[2][2], bH[2][2];

  auto READ_A = [&](bf16x8 (&dst)[4][2], int bufo, int mb) {
#pragma unroll
    for (int m = 0; m < 4; ++m) {
      const char* p = lds + bufo + aoff + (mb + m) * 2048;
      dst[m][0] = __builtin_bit_cast(bf16x8, *(const u16x8*)(p + ck0));
      dst[m][1] = __builtin_bit_cast(bf16x8, *(const u16x8*)(p + ck1));
    }
  };
  auto READ_B = [&](bf16x8 (&dst)[2][2], int bufo, int nb) {
#pragma unroll
    for (int n = 0; n < 2; ++n) {
      const char* p = lds + bufo + boff + (nb + n) * 2048;
      dst[n][0] = __builtin_bit_cast(bf16x8, *(const u16x8*)(p + ck0));
      dst[n][1] = __builtin_bit_cast(bf16x8, *(const u16x8*)(p + ck1));
    }
  };
  auto MFMA_Q = [&](int mb, int nb, bf16x8 (&Af)[4][2], bf16x8 (&Bf)[2][2]) {
    __builtin_amdgcn_s_setprio(1);
#pragma unroll
    for (int kk = 0; kk < 2; ++kk)
#pragma unroll
      for (int m = 0; m < 4; ++m)
#pragma unroll
        for (int n = 0; n < 2; ++n)
          acc[mb + m][nb + n] =
              __builtin_amdgcn_mfma_f32_16x16x32_bf16(Af[m][kk], Bf[n][kk], acc[mb + m][nb + n], 0, 0, 0);
    __builtin_amdgcn_s_setprio(0);
  };

  // ---- prologue: tile0 (B then A) + tile1's B; prefetch Q1(0) frags ----
  STAGE(Bt, bcol,       0, 32768);
  STAGE(Bt, bcol + 128, 0, 49152);
  STAGE(A,  brow,       0, 0);
  STAGE(A,  brow + 128, 0, 16384);
  STAGE(Bt, bcol,       1, 65536 + 32768);
  STAGE(Bt, bcol + 128, 1, 65536 + 49152);
  VMC4();        // drain tile0's 8 loads; tile1's B stays in flight
  barrier_raw();
  READ_A(aQ, 0, 0);
  READ_B(bL0, 0, 0);

  for (int t = 0; t < NT; t += 2) {
    // ================= even iter: cur=buf0, nxt=buf1, bL cur=bL0 =================
    // P1
    if (t + 1 < NT) { STAGE(A, brow, t + 1, 65536); STAGE(A, brow + 128, t + 1, 65536 + 16384); }
    READ_B(bH, 0, 2);
    MFMA_Q(0, 0, aQ, bL0);
    // P2
    READ_A(aR, 0, 4);
    MFMA_Q(0, 2, aQ, bH);
    // P3
    MFMA_Q(4, 2, aR, bH);
    barrier_raw();
    // P4
    if (t + 2 < NT) {
      STAGE(Bt, bcol, t + 2, 32768); STAGE(Bt, bcol + 128, t + 2, 49152);
      VMC4();
    } else if (t + 1 < NT) {
      VMC0();
    }
    barrier_raw();
    if (t + 1 < NT) { READ_A(aQ, 65536, 0); READ_B(bL1, 65536, 0); }
    MFMA_Q(4, 0, aR, bL0);

    // ================= odd iter t+1: cur=buf1, nxt=buf0, bL cur=bL1 =================
    if (t + 1 < NT) {
      // P1
      if (t + 2 < NT) { STAGE(A, brow, t + 2, 0); STAGE(A, brow + 128, t + 2, 16384); }
      READ_B(bH, 65536, 2);
      MFMA_Q(0, 0, aQ, bL1);
      // P2
      READ_A(aR, 65536, 4);
      MFMA_Q(0, 2, aQ, bH);
      // P3
      MFMA_Q(4, 2, aR, bH);
      barrier_raw();
      // P4
      if (t + 3 < NT) {
        STAGE(Bt, bcol, t + 3, 65536 + 32768); STAGE(Bt, bcol + 128, t + 3, 65536 + 49152);
        VMC4();
      } else if (t + 2 < NT) {
        VMC0();
      }
      barrier_raw();
      if (t + 2 < NT) { READ_A(aQ, 0, 0); READ_B(bL0, 0, 0); }
      MFMA_Q(4, 0, aR, bL1);
    }
  }
}

// ---------------- GEMM1: qkv = x @ W_qkv, epilogue elu+1 on q,k; scatter (B,H,N,D) ----------------
__global__ __launch_bounds__(512, 2) void gemm_qkv(
    const unsigned short* __restrict__ xbf, const unsigned short* __restrict__ wt,
    unsigned short* __restrict__ q, unsigned short* __restrict__ k, unsigned short* __restrict__ v) {
  __shared__ __align__(16) char lds[131072];
  f32x4 acc[8][4] = {};
  // L2-patch grid: XCD r owns tm stripe [8r,8r+8), tn-major within the stripe.
  const int bid = blockIdx.x;                    // 768 = 8 XCD x 8 tm x 12 tn
  const int r = bid & 7, i = bid >> 3;
  const int tm = r * 8 + (i & 7);
  const int tn = i >> 3;
  const int brow = tm * 256, bcol = tn * 256;
  gemm256_mainloop(xbf, wt, brow, bcol, lds, acc);

  const int lane = threadIdx.x & 63, w = threadIdx.x >> 6;
  const int wr = w >> 2, wc = w & 3;
  const int lr = lane & 15, kg = lane >> 4;
#pragma unroll
  for (int m = 0; m < 8; ++m)
#pragma unroll
    for (int n = 0; n < 4; ++n)
#pragma unroll
      for (int rr = 0; rr < 4; ++rr) {
        int grow = brow + wr * 128 + m * 16 + kg * 4 + rr;
        int gcol = bcol + wc * 64 + n * 16 + lr;
        float val = acc[m][n][rr];
        int tt = gcol >> 10;
        int h = (gcol >> 6) & 15;
        int d = gcol & 63;
        int b = grow >> 12, s = grow & 4095;
        size_t idx = ((size_t)(b * 16 + h) * 4096 + s) * 64 + d;
        if (tt < 2) {
          val = val > 0.f ? val + 1.f : __expf(val);  // elu(x)+1
          (tt == 0 ? q : k)[idx] = f2bf(val);
        } else {
          v[idx] = f2bf(val);
        }
      }
}

// ---------------- GEMM2: out = attn @ W_out + b ----------------
__global__ __launch_bounds__(512, 2) void gemm_out(
    const unsigned short* __restrict__ attn, const unsigned short* __restrict__ wt,
    const float* __restrict__ bias, float* __restrict__ out) {
  __shared__ __align__(16) char lds[131072];
  f32x4 acc[8][4] = {};
  const int bid = blockIdx.x;                    // 256 = 8 XCD x 8 tm x 4 tn
  const int r = bid & 7, i = bid >> 3;
  const int tm = r * 8 + (i & 7);
  const int tn = i >> 3;
  const int brow = tm * 256, bcol = tn * 256;
  gemm256_mainloop(attn, wt, brow, bcol, lds, acc);

  const int lane = threadIdx.x & 63, w = threadIdx.x >> 6;
  const int wr = w >> 2, wc = w & 3;
  const int lr = lane & 15, kg = lane >> 4;
#pragma unroll
  for (int m = 0; m < 8; ++m)
#pragma unroll
    for (int n = 0; n < 4; ++n)
#pragma unroll
      for (int rr = 0; rr < 4; ++rr) {
        int grow = brow + wr * 128 + m * 16 + kg * 4 + rr;
        int gcol = bcol + wc * 64 + n * 16 + lr;
        out[(size_t)grow * 1024 + gcol] = acc[m][n][rr] + bias[gcol];
      }
}

// ---------------- kv[d][e] = sum_n k[n][d] v[n][e]  (stored [e][d]); ksum[d] ----------------
__global__ __launch_bounds__(256) void kv_kernel(
    const unsigned short* __restrict__ k, const unsigned short* __restrict__ v,
    float* __restrict__ kv, float* __restrict__ ksum) {
  const int bid = blockIdx.x;             // B*H*8 = 512
  const int bh = bid >> 3, chunk = bid & 7;
  const unsigned short* kb = k + (size_t)bh * 4096 * 64 + chunk * 512 * 64;
  const unsigned short* vb = v + (size_t)bh * 4096 * 64 + chunk * 512 * 64;
  __shared__ unsigned short ks[64 * 64];
  __shared__ unsigned short vs[64 * 64];
  const int tid = threadIdx.x;
  const int ty = tid >> 4, tx = tid & 15;
  float acc[4][4] = {};
  float ksacc[4] = {};
  for (int t = 0; t < 8; ++t) {
    const unsigned short* ksrc = kb + t * 4096;
    const unsigned short* vsrc = vb + t * 4096;
    *reinterpret_cast<u16x8*>(&ks[tid * 8])        = *reinterpret_cast<const u16x8*>(ksrc + tid * 8);
    *reinterpret_cast<u16x8*>(&ks[2048 + tid * 8]) = *reinterpret_cast<const u16x8*>(ksrc + 2048 + tid * 8);
    *reinterpret_cast<u16x8*>(&vs[tid * 8])        = *reinterpret_cast<const u16x8*>(vsrc + tid * 8);
    *reinterpret_cast<u16x8*>(&vs[2048 + tid * 8]) = *reinterpret_cast<const u16x8*>(vsrc + 2048 + tid * 8);
    __syncthreads();
#pragma unroll 4
    for (int nn = 0; nn < 64; ++nn) {
      u16x4 ku = *reinterpret_cast<const u16x4*>(&ks[nn * 64 + ty * 4]);
      u16x4 vu = *reinterpret_cast<const u16x4*>(&vs[nn * 64 + tx * 4]);
      float kd[4], ve[4];
#pragma unroll
      for (int i = 0; i < 4; ++i) { kd[i] = bf2f(ku[i]); ve[i] = bf2f(vu[i]); }
#pragma unroll
      for (int i = 0; i < 4; ++i) ksacc[i] += kd[i];
#pragma unroll
      for (int i = 0; i < 4; ++i)
#pragma unroll
        for (int j = 0; j < 4; ++j) acc[i][j] += kd[i] * ve[j];
    }
    __syncthreads();
  }
  float* kvb = kv + (size_t)bh * 4096;
#pragma unroll
  for (int i = 0; i < 4; ++i)
#pragma unroll
    for (int j = 0; j < 4; ++j)
      atomicAdd(&kvb[(tx * 4 + j) * 64 + ty * 4 + i], acc[i][j]);  // [e][d]
  if (tx == 0) {
#pragma unroll
    for (int i = 0; i < 4; ++i) atomicAdd(&ksum[bh * 64 + ty * 4 + i], ksacc[i]);
  }
}

// ---------------- num = q @ kv ; attn = num / (q.ksum + 1e-6) ----------------
__global__ __launch_bounds__(256) void num_kernel(
    const unsigned short* __restrict__ q, const float* __restrict__ kv,
    const float* __restrict__ ksum, unsigned short* __restrict__ attn) {
  const int bid = blockIdx.x;              // B*H*64 = 4096
  const int bh = bid >> 6, sblk = bid & 63;
  const int b = bh >> 4, h = bh & 15;
  __shared__ unsigned short kvs[64 * 72];
  __shared__ float ksum_s[64];
  __shared__ float norm_s[64];
  const int tid = threadIdx.x;
  const float* kvb = kv + (size_t)bh * 4096;
#pragma unroll
  for (int r = 0; r < 4; ++r) {
    int e = r * 1024 + tid * 4;
    float4 f = *reinterpret_cast<const float4*>(&kvb[e]);
    int row = e >> 6, col = e & 63;
    u16x4 o = { f2bf(f.x), f2bf(f.y), f2bf(f.z), f2bf(f.w) };
    *reinterpret_cast<u16x4*>(&kvs[row * 72 + col]) = o;
  }
  if (tid < 16) {
    float4 f = *reinterpret_cast<const float4*>(&ksum[bh * 64 + tid * 4]);
    ksum_s[tid * 4 + 0] = f.x; ksum_s[tid * 4 + 1] = f.y;
    ksum_s[tid * 4 + 2] = f.z; ksum_s[tid * 4 + 3] = f.w;
  }
  __syncthreads();

  const int lane = tid & 63, w = tid >> 6;
  const int lr = lane & 15, kg = lane >> 4;
  const int s0 = sblk * 64 + w * 16;
  const unsigned short* qrow = q + ((size_t)bh * 4096 + s0 + lr) * 64 + kg * 8;
  u16x8 a0u = *reinterpret_cast<const u16x8*>(qrow);
  u16x8 a1u = *reinterpret_cast<const u16x8*>(qrow + 32);
  bf16x8 a0 = __builtin_bit_cast(bf16x8, a0u);
  bf16x8 a1 = __builtin_bit_cast(bf16x8, a1u);

  float p = 0.f;
#pragma unroll
  for (int j = 0; j < 8; ++j) {
    p += bf2f(a0u[j]) * ksum_s[kg * 8 + j];
    p += bf2f(a1u[j]) * ksum_s[32 + kg * 8 + j];
  }
  p += __shfl_xor(p, 16);
  p += __shfl_xor(p, 32);
  if (kg == 0) norm_s[w * 16 + lr] = p;

  f32x4 accs[4];
#pragma unroll
  for (int jf = 0; jf < 4; ++jf) {
    u16x8 b0u = *reinterpret_cast<const u16x8*>(&kvs[(jf * 16 + lr) * 72 + kg * 8]);
    u16x8 b1u = *reinterpret_cast<const u16x8*>(&kvs[(jf * 16 + lr) * 72 + 32 + kg * 8]);
    f32x4 c = {0.f, 0.f, 0.f, 0.f};
    c = __builtin_amdgcn_mfma_f32_16x16x32_bf16(a0, __builtin_bit_cast(bf16x8, b0u), c, 0, 0, 0);
    c = __builtin_amdgcn_mfma_f32_16x16x32_bf16(a1, __builtin_bit_cast(bf16x8, b1u), c, 0, 0, 0);
    accs[jf] = c;
  }
  float dn[4];
#pragma unroll
  for (int r = 0; r < 4; ++r) dn[r] = norm_s[w * 16 + kg * 4 + r] + 1e-6f;

  unsigned short* ab = attn + (size_t)b * 4096 * 1024 + h * 64;
#pragma unroll
  for (int jf = 0; jf < 4; ++jf)
#pragma unroll
    for (int r = 0; r < 4; ++r) {
      int s = s0 + kg * 4 + r;
      int e2 = jf * 16 + lr;
      ab[(size_t)s * 1024 + e2] = f2bf(accs[jf][r] / dn[r]);
    }
}

extern "C" void kernel_launch(void* const* d_in, const int* in_sizes, int n_in,
                              void* d_out, int out_size, void* d_ws, size_t ws_size,
                              hipStream_t stream) {
  const float* x     = (const float*)d_in[0];
  const float* W_qkv = (const float*)d_in[1];
  const float* W_out = (const float*)d_in[2];
  const float* b_out = (const float*)d_in[3];
  float* out = (float*)d_out;

  unsigned short* xbf   = (unsigned short*)d_ws;            // 16384*1024
  unsigned short* attnb = xbf;                               // alias (xbf dead after gemm_qkv)
  unsigned short* wqkvT = xbf + 16777216;                    // 3072*1024
  unsigned short* woutT = wqkvT + 3145728;                   // 1024*1024
  unsigned short* qb    = woutT + 1048576;                   // 16777216
  unsigned short* kb    = qb + 16777216;
  unsigned short* vb    = kb + 16777216;
  float* kvw            = (float*)(vb + 16777216);           // 262144 f32
  float* ksumw          = kvw + 262144;                      // 4096 f32

  conv_f32_bf16<<<2048, 256, 0, stream>>>(x, xbf, 16777216);
  transpose_f32_bf16<<<dim3(48, 16), 256, 0, stream>>>(W_qkv, wqkvT, 1024, 3072);
  transpose_f32_bf16<<<dim3(16, 16), 256, 0, stream>>>(W_out, woutT, 1024, 1024);
  hipMemsetAsync(kvw, 0, (262144 + 4096) * sizeof(float), stream);
  gemm_qkv<<<768, 512, 0, stream>>>(xbf, wqkvT, qb, kb, vb);
  kv_kernel<<<512, 256, 0, stream>>>(kb, vb, kvw, ksumw);
  num_kernel<<<4096, 256, 0, stream>>>(qb, kvw, ksumw, attnb);
  gemm_out<<<256, 512, 0, stream>>>(attnb, woutT, b_out, out);
}

// Round 7
// 264.222 us; speedup vs baseline: 1.2111x; 1.2111x over previous
//
#include <hip/hip_runtime.h>
#include <hip/hip_bf16.h>

using bf16x8 = __bf16 __attribute__((ext_vector_type(8)));
using f32x4  = float  __attribute__((ext_vector_type(4)));
using u16x8  = unsigned short __attribute__((ext_vector_type(8)));
using u16x4  = unsigned short __attribute__((ext_vector_type(4)));

__device__ __forceinline__ unsigned short f2bf(float f) {
  unsigned u = __builtin_bit_cast(unsigned, f);
  u += 0x7fffu + ((u >> 16) & 1u);
  return (unsigned short)(u >> 16);
}
__device__ __forceinline__ float bf2f(unsigned short h) {
  return __builtin_bit_cast(float, (unsigned)h << 16);
}

__device__ __forceinline__ void gload16(const void* g, void* l) {
  __builtin_amdgcn_global_load_lds(
      (const __attribute__((address_space(1))) void*)g,
      (__attribute__((address_space(3))) void*)l, 16, 0, 0);
}

__device__ __forceinline__ void barrier_raw() {
  asm volatile("" ::: "memory");
  __builtin_amdgcn_s_barrier();
  asm volatile("" ::: "memory");
}
#define VMC4() asm volatile("s_waitcnt vmcnt(4)" ::: "memory")
#define VMC0() asm volatile("s_waitcnt vmcnt(0)" ::: "memory")
#define SGB(mask, n) __builtin_amdgcn_sched_group_barrier(mask, n, 0)

// ---------------- convert f32 -> bf16 (vectorized) ----------------
__global__ __launch_bounds__(256) void conv_f32_bf16(const float* __restrict__ in,
                                                     unsigned short* __restrict__ out, int n) {
  int stride = gridDim.x * 256 * 4;
  for (int i = (blockIdx.x * 256 + threadIdx.x) * 4; i < n; i += stride) {
    float4 v = *reinterpret_cast<const float4*>(in + i);
    u16x4 o = { f2bf(v.x), f2bf(v.y), f2bf(v.z), f2bf(v.w) };
    *reinterpret_cast<u16x4*>(out + i) = o;
  }
}

// ---------------- transpose + convert: out[c][r] = bf16(in[r][c]) ----------------
__global__ __launch_bounds__(256) void transpose_f32_bf16(const float* __restrict__ in,
                                                          unsigned short* __restrict__ out,
                                                          int R, int C) {
  __shared__ float t[64][65];
  int c0 = blockIdx.x * 64, r0 = blockIdx.y * 64;
  int lx = threadIdx.x & 63, ly = threadIdx.x >> 6;
#pragma unroll
  for (int i = 0; i < 16; ++i) {
    int r = ly * 16 + i;
    t[r][lx] = in[(size_t)(r0 + r) * C + c0 + lx];
  }
  __syncthreads();
#pragma unroll
  for (int i = 0; i < 16; ++i) {
    int c = ly * 16 + i;
    out[(size_t)(c0 + c) * R + r0 + lx] = f2bf(t[lx][c]);
  }
}

// ============ 256x256, BK=64, 8-wave, software-pipelined GEMM mainloop ============
// Same schedule/staging/vmcnt ledger as round-5 (verified), with:
//  - all ds_read addresses precomputed once (8 base ptrs, imm offsets only)
//  - global staging ptrs bumped (+128B/K-step), second gload at +131072 const
//  - sched_group_barrier 12x{DS_READ 1, MFMA 4} pinning read||MFMA interleave
//  - setprio at region granularity
__device__ __forceinline__ void gemm256_mainloop(
    const unsigned short* __restrict__ A, const unsigned short* __restrict__ Bt,
    int brow, int bcol, char* lds, f32x4 (&acc)[8][4]) {
  constexpr int NT = 16;  // K = 1024 / 64
  const int tid  = threadIdx.x;
  const int lane = tid & 63;
  const int w    = tid >> 6;
  const int wr   = w >> 2, wc = w & 3;
  const int lr   = lane & 15, kg = lane >> 4;

  // staging: LDS dest is linear (tid*16); global source is inverse-swizzled.
  // off0 = global byte offset (row stride 2048B) for LDS byte tid*16.
  const int o0 = tid * 16;
  const int p0 = o0 ^ (((o0 >> 7) & 7) << 4);
  const int off0 = (p0 >> 7) * 2048 + (p0 & 127);
  const int wq = w << 10;

  // swizzled read addressing: ck1 = ck0 ^ 64 (row-XOR involution)
  const int xr  = (lr & 7) << 4;
  const int ck0 = (kg * 16) ^ xr;
  const int aoff = wr * 16384 + lr * 128;
  const int boff = 32768 + (wc >> 1) * 16384 + (wc & 1) * 8192 + lr * 128;

  const char* rA00 = lds + aoff + ck0;
  const char* rA01 = lds + aoff + (ck0 ^ 64);
  const char* rA10 = rA00 + 65536;
  const char* rA11 = rA01 + 65536;
  const char* rB00 = lds + boff + ck0;
  const char* rB01 = lds + boff + (ck0 ^ 64);
  const char* rB10 = rB00 + 65536;
  const char* rB11 = rB01 + 65536;

  const char* gA0 = (const char*)(A  + (size_t)brow * 1024) + off0;
  const char* gA1 = (const char*)(A  + (size_t)(brow + 128) * 1024) + off0;
  const char* gB0 = (const char*)(Bt + (size_t)bcol * 1024) + off0;
  const char* gB1 = (const char*)(Bt + (size_t)(bcol + 128) * 1024) + off0;

  auto STG = [&](const char*& g, int region) {
    gload16(g, lds + region + wq);
    gload16(g + 131072, lds + region + 8192 + wq);  // rows 64-127: +64*2048
    g += 128;                                        // next K-step (64 elems)
  };

  bf16x8 aQ[4][2], aR[4][2], bL0[2][2], bL1[2][2], bH[2][2];

  auto READ_A = [&](bf16x8 (&dst)[4][2], const char* pk0, const char* pk1, int mb) {
#pragma unroll
    for (int m = 0; m < 4; ++m) {
      dst[m][0] = __builtin_bit_cast(bf16x8, *(const u16x8*)(pk0 + (mb + m) * 2048));
      dst[m][1] = __builtin_bit_cast(bf16x8, *(const u16x8*)(pk1 + (mb + m) * 2048));
    }
  };
  auto READ_B = [&](bf16x8 (&dst)[2][2], const char* pk0, const char* pk1, int nb) {
#pragma unroll
    for (int n = 0; n < 2; ++n) {
      dst[n][0] = __builtin_bit_cast(bf16x8, *(const u16x8*)(pk0 + (nb + n) * 2048));
      dst[n][1] = __builtin_bit_cast(bf16x8, *(const u16x8*)(pk1 + (nb + n) * 2048));
    }
  };
  auto MFMA_Q = [&](int mb, int nb, bf16x8 (&Af)[4][2], bf16x8 (&Bf)[2][2]) {
#pragma unroll
    for (int kk = 0; kk < 2; ++kk)
#pragma unroll
      for (int m = 0; m < 4; ++m)
#pragma unroll
        for (int n = 0; n < 2; ++n)
          acc[mb + m][nb + n] =
              __builtin_amdgcn_mfma_f32_16x16x32_bf16(Af[m][kk], Bf[n][kk], acc[mb + m][nb + n], 0, 0, 0);
  };
  // interleave directive for the P1-P3 block: exactly 12 ds_reads + 48 MFMAs
  auto INTERLEAVE_P123 = [&]() {
#pragma unroll
    for (int s = 0; s < 12; ++s) { SGB(0x100, 1); SGB(0x8, 4); }
  };

  // ---- prologue: tile0 (B then A) + tile1's B; prefetch Q1(0) frags ----
  STG(gB0, 32768); STG(gB1, 49152);
  STG(gA0, 0);     STG(gA1, 16384);
  STG(gB0, 65536 + 32768); STG(gB1, 65536 + 49152);
  VMC4();        // drain tile0's 8 loads; tile1's B stays in flight
  barrier_raw();
  READ_A(aQ, rA00, rA01, 0);
  READ_B(bL0, rB00, rB01, 0);
  __builtin_amdgcn_s_setprio(1);

  for (int t = 0; t < NT; t += 2) {
    // ================= even iter: cur=buf0, nxt=buf1, bL cur=bL0 =================
    // P1: stage A(t+1)->buf1; read bH(cur); MFMA Q1
    if (t + 1 < NT) { STG(gA0, 65536); STG(gA1, 65536 + 16384); }
    READ_B(bH, rB00, rB01, 2);
    MFMA_Q(0, 0, aQ, bL0);
    // P2: read aR(cur); MFMA Q2
    READ_A(aR, rA00, rA01, 4);
    MFMA_Q(0, 2, aQ, bH);
    // P3: MFMA Q3
    MFMA_Q(4, 2, aR, bH);
    INTERLEAVE_P123();
    __builtin_amdgcn_s_setprio(0);
    barrier_raw();
    // P4: stage B(t+2)->buf0; counted vmcnt; reads of next step overlap Q4
    if (t + 2 < NT) {
      STG(gB0, 32768); STG(gB1, 49152);
      VMC4();
    } else if (t + 1 < NT) {
      VMC0();
    }
    barrier_raw();
    __builtin_amdgcn_s_setprio(1);
    if (t + 1 < NT) { READ_A(aQ, rA10, rA11, 0); READ_B(bL1, rB10, rB11, 0); }
    MFMA_Q(4, 0, aR, bL0);

    // ================= odd iter t+1: cur=buf1, nxt=buf0, bL cur=bL1 =================
    if (t + 1 < NT) {
      // P1
      if (t + 2 < NT) { STG(gA0, 0); STG(gA1, 16384); }
      READ_B(bH, rB10, rB11, 2);
      MFMA_Q(0, 0, aQ, bL1);
      // P2
      READ_A(aR, rA10, rA11, 4);
      MFMA_Q(0, 2, aQ, bH);
      // P3
      MFMA_Q(4, 2, aR, bH);
      INTERLEAVE_P123();
      __builtin_amdgcn_s_setprio(0);
      barrier_raw();
      // P4
      if (t + 3 < NT) {
        STG(gB0, 65536 + 32768); STG(gB1, 65536 + 49152);
        VMC4();
      } else if (t + 2 < NT) {
        VMC0();
      }
      barrier_raw();
      __builtin_amdgcn_s_setprio(1);
      if (t + 2 < NT) { READ_A(aQ, rA00, rA01, 0); READ_B(bL0, rB00, rB01, 0); }
      MFMA_Q(4, 0, aR, bL1);
    }
  }
  __builtin_amdgcn_s_setprio(0);
}

// ---------------- GEMM1: qkv = x @ W_qkv, epilogue elu+1 on q,k; scatter (B,H,N,D) ----------------
__global__ __launch_bounds__(512, 2) void gemm_qkv(
    const unsigned short* __restrict__ xbf, const unsigned short* __restrict__ wt,
    unsigned short* __restrict__ q, unsigned short* __restrict__ k, unsigned short* __restrict__ v) {
  __shared__ __align__(16) char lds[131072];
  f32x4 acc[8][4] = {};
  // L2-patch grid: XCD r owns tm stripe [8r,8r+8), tn-major within the stripe.
  const int bid = blockIdx.x;                    // 768 = 8 XCD x 8 tm x 12 tn
  const int r = bid & 7, i = bid >> 3;
  const int tm = r * 8 + (i & 7);
  const int tn = i >> 3;
  const int brow = tm * 256, bcol = tn * 256;
  gemm256_mainloop(xbf, wt, brow, bcol, lds, acc);

  const int lane = threadIdx.x & 63, w = threadIdx.x >> 6;
  const int wr = w >> 2, wc = w & 3;
  const int lr = lane & 15, kg = lane >> 4;
#pragma unroll
  for (int m = 0; m < 8; ++m)
#pragma unroll
    for (int n = 0; n < 4; ++n)
#pragma unroll
      for (int rr = 0; rr < 4; ++rr) {
        int grow = brow + wr * 128 + m * 16 + kg * 4 + rr;
        int gcol = bcol + wc * 64 + n * 16 + lr;
        float val = acc[m][n][rr];
        int tt = gcol >> 10;
        int h = (gcol >> 6) & 15;
        int d = gcol & 63;
        int b = grow >> 12, s = grow & 4095;
        size_t idx = ((size_t)(b * 16 + h) * 4096 + s) * 64 + d;
        if (tt < 2) {
          val = val > 0.f ? val + 1.f : __expf(val);  // elu(x)+1
          (tt == 0 ? q : k)[idx] = f2bf(val);
        } else {
          v[idx] = f2bf(val);
        }
      }
}

// ---------------- GEMM2: out = attn @ W_out + b ----------------
__global__ __launch_bounds__(512, 2) void gemm_out(
    const unsigned short* __restrict__ attn, const unsigned short* __restrict__ wt,
    const float* __restrict__ bias, float* __restrict__ out) {
  __shared__ __align__(16) char lds[131072];
  f32x4 acc[8][4] = {};
  const int bid = blockIdx.x;                    // 256 = 8 XCD x 8 tm x 4 tn
  const int r = bid & 7, i = bid >> 3;
  const int tm = r * 8 + (i & 7);
  const int tn = i >> 3;
  const int brow = tm * 256, bcol = tn * 256;
  gemm256_mainloop(attn, wt, brow, bcol, lds, acc);

  const int lane = threadIdx.x & 63, w = threadIdx.x >> 6;
  const int wr = w >> 2, wc = w & 3;
  const int lr = lane & 15, kg = lane >> 4;
#pragma unroll
  for (int m = 0; m < 8; ++m)
#pragma unroll
    for (int n = 0; n < 4; ++n)
#pragma unroll
      for (int rr = 0; rr < 4; ++rr) {
        int grow = brow + wr * 128 + m * 16 + kg * 4 + rr;
        int gcol = bcol + wc * 64 + n * 16 + lr;
        out[(size_t)grow * 1024 + gcol] = acc[m][n][rr] + bias[gcol];
      }
}

// ---------------- kv[d][e] = sum_n k[n][d] v[n][e]  (stored [e][d]); ksum[d] ----------------
__global__ __launch_bounds__(256) void kv_kernel(
    const unsigned short* __restrict__ k, const unsigned short* __restrict__ v,
    float* __restrict__ kv, float* __restrict__ ksum) {
  const int bid = blockIdx.x;             // B*H*8 = 512
  const int bh = bid >> 3, chunk = bid & 7;
  const unsigned short* kb = k + (size_t)bh * 4096 * 64 + chunk * 512 * 64;
  const unsigned short* vb = v + (size_t)bh * 4096 * 64 + chunk * 512 * 64;
  __shared__ unsigned short ks[64 * 64];
  __shared__ unsigned short vs[64 * 64];
  const int tid = threadIdx.x;
  const int ty = tid >> 4, tx = tid & 15;
  float acc[4][4] = {};
  float ksacc[4] = {};
  for (int t = 0; t < 8; ++t) {
    const unsigned short* ksrc = kb + t * 4096;
    const unsigned short* vsrc = vb + t * 4096;
    *reinterpret_cast<u16x8*>(&ks[tid * 8])        = *reinterpret_cast<const u16x8*>(ksrc + tid * 8);
    *reinterpret_cast<u16x8*>(&ks[2048 + tid * 8]) = *reinterpret_cast<const u16x8*>(ksrc + 2048 + tid * 8);
    *reinterpret_cast<u16x8*>(&vs[tid * 8])        = *reinterpret_cast<const u16x8*>(vsrc + tid * 8);
    *reinterpret_cast<u16x8*>(&vs[2048 + tid * 8]) = *reinterpret_cast<const u16x8*>(vsrc + 2048 + tid * 8);
    __syncthreads();
#pragma unroll 4
    for (int nn = 0; nn < 64; ++nn) {
      u16x4 ku = *reinterpret_cast<const u16x4*>(&ks[nn * 64 + ty * 4]);
      u16x4 vu = *reinterpret_cast<const u16x4*>(&vs[nn * 64 + tx * 4]);
      float kd[4], ve[4];
#pragma unroll
      for (int i = 0; i < 4; ++i) { kd[i] = bf2f(ku[i]); ve[i] = bf2f(vu[i]); }
#pragma unroll
      for (int i = 0; i < 4; ++i) ksacc[i] += kd[i];
#pragma unroll
      for (int i = 0; i < 4; ++i)
#pragma unroll
        for (int j = 0; j < 4; ++j) acc[i][j] += kd[i] * ve[j];
    }
    __syncthreads();
  }
  float* kvb = kv + (size_t)bh * 4096;
#pragma unroll
  for (int i = 0; i < 4; ++i)
#pragma unroll
    for (int j = 0; j < 4; ++j)
      atomicAdd(&kvb[(tx * 4 + j) * 64 + ty * 4 + i], acc[i][j]);  // [e][d]
  if (tx == 0) {
#pragma unroll
    for (int i = 0; i < 4; ++i) atomicAdd(&ksum[bh * 64 + ty * 4 + i], ksacc[i]);
  }
}

// ---------------- num = q @ kv ; attn = num / (q.ksum + 1e-6) ----------------
__global__ __launch_bounds__(256) void num_kernel(
    const unsigned short* __restrict__ q, const float* __restrict__ kv,
    const float* __restrict__ ksum, unsigned short* __restrict__ attn) {
  const int bid = blockIdx.x;              // B*H*64 = 4096
  const int bh = bid >> 6, sblk = bid & 63;
  const int b = bh >> 4, h = bh & 15;
  __shared__ unsigned short kvs[64 * 72];
  __shared__ float ksum_s[64];
  __shared__ float norm_s[64];
  const int tid = threadIdx.x;
  const float* kvb = kv + (size_t)bh * 4096;
#pragma unroll
  for (int r = 0; r < 4; ++r) {
    int e = r * 1024 + tid * 4;
    float4 f = *reinterpret_cast<const float4*>(&kvb[e]);
    int row = e >> 6, col = e & 63;
    u16x4 o = { f2bf(f.x), f2bf(f.y), f2bf(f.z), f2bf(f.w) };
    *reinterpret_cast<u16x4*>(&kvs[row * 72 + col]) = o;
  }
  if (tid < 16) {
    float4 f = *reinterpret_cast<const float4*>(&ksum[bh * 64 + tid * 4]);
    ksum_s[tid * 4 + 0] = f.x; ksum_s[tid * 4 + 1] = f.y;
    ksum_s[tid * 4 + 2] = f.z; ksum_s[tid * 4 + 3] = f.w;
  }
  __syncthreads();

  const int lane = tid & 63, w = tid >> 6;
  const int lr = lane & 15, kg = lane >> 4;
  const int s0 = sblk * 64 + w * 16;
  const unsigned short* qrow = q + ((size_t)bh * 4096 + s0 + lr) * 64 + kg * 8;
  u16x8 a0u = *reinterpret_cast<const u16x8*>(qrow);
  u16x8 a1u = *reinterpret_cast<const u16x8*>(qrow + 32);
  bf16x8 a0 = __builtin_bit_cast(bf16x8, a0u);
  bf16x8 a1 = __builtin_bit_cast(bf16x8, a1u);

  float p = 0.f;
#pragma unroll
  for (int j = 0; j < 8; ++j) {
    p += bf2f(a0u[j]) * ksum_s[kg * 8 + j];
    p += bf2f(a1u[j]) * ksum_s[32 + kg * 8 + j];
  }
  p += __shfl_xor(p, 16);
  p += __shfl_xor(p, 32);
  if (kg == 0) norm_s[w * 16 + lr] = p;

  f32x4 accs[4];
#pragma unroll
  for (int jf = 0; jf < 4; ++jf) {
    u16x8 b0u = *reinterpret_cast<const u16x8*>(&kvs[(jf * 16 + lr) * 72 + kg * 8]);
    u16x8 b1u = *reinterpret_cast<const u16x8*>(&kvs[(jf * 16 + lr) * 72 + 32 + kg * 8]);
    f32x4 c = {0.f, 0.f, 0.f, 0.f};
    c = __builtin_amdgcn_mfma_f32_16x16x32_bf16(a0, __builtin_bit_cast(bf16x8, b0u), c, 0, 0, 0);
    c = __builtin_amdgcn_mfma_f32_16x16x32_bf16(a1, __builtin_bit_cast(bf16x8, b1u), c, 0, 0, 0);
    accs[jf] = c;
  }
  float dn[4];
#pragma unroll
  for (int r = 0; r < 4; ++r) dn[r] = norm_s[w * 16 + kg * 4 + r] + 1e-6f;

  unsigned short* ab = attn + (size_t)b * 4096 * 1024 + h * 64;
#pragma unroll
  for (int jf = 0; jf < 4; ++jf)
#pragma unroll
    for (int r = 0; r < 4; ++r) {
      int s = s0 + kg * 4 + r;
      int e2 = jf * 16 + lr;
      ab[(size_t)s * 1024 + e2] = f2bf(accs[jf][r] / dn[r]);
    }
}

extern "C" void kernel_launch(void* const* d_in, const int* in_sizes, int n_in,
                              void* d_out, int out_size, void* d_ws, size_t ws_size,
                              hipStream_t stream) {
  const float* x     = (const float*)d_in[0];
  const float* W_qkv = (const float*)d_in[1];
  const float* W_out = (const float*)d_in[2];
  const float* b_out = (const float*)d_in[3];
  float* out = (float*)d_out;

  unsigned short* xbf   = (unsigned short*)d_ws;            // 16384*1024
  unsigned short* attnb = xbf;                               // alias (xbf dead after gemm_qkv)
  unsigned short* wqkvT = xbf + 16777216;                    // 3072*1024
  unsigned short* woutT = wqkvT + 3145728;                   // 1024*1024
  unsigned short* qb    = woutT + 1048576;                   // 16777216
  unsigned short* kb    = qb + 16777216;
  unsigned short* vb    = kb + 16777216;
  float* kvw            = (float*)(vb + 16777216);           // 262144 f32
  float* ksumw          = kvw + 262144;                      // 4096 f32

  conv_f32_bf16<<<2048, 256, 0, stream>>>(x, xbf, 16777216);
  transpose_f32_bf16<<<dim3(48, 16), 256, 0, stream>>>(W_qkv, wqkvT, 1024, 3072);
  transpose_f32_bf16<<<dim3(16, 16), 256, 0, stream>>>(W_out, woutT, 1024, 1024);
  hipMemsetAsync(kvw, 0, (262144 + 4096) * sizeof(float), stream);
  gemm_qkv<<<768, 512, 0, stream>>>(xbf, wqkvT, qb, kb, vb);
  kv_kernel<<<512, 256, 0, stream>>>(kb, vb, kvw, ksumw);
  num_kernel<<<4096, 256, 0, stream>>>(qb, kvw, ksumw, attnb);
  gemm_out<<<256, 512, 0, stream>>>(attnb, woutT, b_out, out);
}